// Round 1
// baseline (407.848 us; speedup 1.0000x reference)
//
#include <hip/hip_runtime.h>
#include <hip/hip_bf16.h>

#define NUM_NODES 50000
#define NODE_DIM 32
#define EDGE_DIM 7
#define HIDDEN_DIM 64
#define NUM_EDGES 200000

// ---------------------------------------------------------------------------
// K_A: agg[n][o] = conv_bias[o] + sum_i x[n][i] * root_w[i][o]
// one wave per node, lane = output channel o (64 == wave size)
// ---------------------------------------------------------------------------
__global__ __launch_bounds__(256) void k_init(const float* __restrict__ x,
                                              const float* __restrict__ root_w,
                                              const float* __restrict__ conv_bias,
                                              float* __restrict__ agg) {
    __shared__ float rw[NODE_DIM * HIDDEN_DIM];
    __shared__ float cb[HIDDEN_DIM];
    for (int t = threadIdx.x; t < NODE_DIM * HIDDEN_DIM; t += blockDim.x) rw[t] = root_w[t];
    if (threadIdx.x < HIDDEN_DIM) cb[threadIdx.x] = conv_bias[threadIdx.x];
    __syncthreads();

    const int lane   = threadIdx.x & 63;
    const int wave   = (blockIdx.x * blockDim.x + threadIdx.x) >> 6;
    const int nwaves = (gridDim.x * blockDim.x) >> 6;

    for (int n = wave; n < NUM_NODES; n += nwaves) {
        float acc = cb[lane];
        const float* xr = x + n * NODE_DIM;
        #pragma unroll
        for (int i = 0; i < NODE_DIM; ++i)
            acc = fmaf(xr[i], rw[i * HIDDEN_DIM + lane], acc);
        agg[n * HIDDEN_DIM + lane] = acc;
    }
}

// ---------------------------------------------------------------------------
// K_B: fused NNConv message + scatter.
//   w_edge[i][o] = relu(b_nn[i*64+o] + sum_k e[k]*w_nn[k][i*64+o])
//   msg[o]       = sum_i x[src][i] * w_edge[i][o]
//   atomicAdd(agg[dst][o], msg[o])
// one wave handles M=4 edges, lane = output channel o.
// w_nn (57KB) + b_nn (8KB) staged in LDS, lane-consecutive (conflict-free).
// ---------------------------------------------------------------------------
#define MB 4
__global__ __launch_bounds__(512) void k_msg(const int* __restrict__ ei,
                                             const float* __restrict__ ea,
                                             const float* __restrict__ x,
                                             const float* __restrict__ w_nn,
                                             const float* __restrict__ b_nn,
                                             float* __restrict__ agg) {
    __shared__ float wS[EDGE_DIM * NODE_DIM * HIDDEN_DIM];  // 7*2048 floats = 57344B
    __shared__ float bS[NODE_DIM * HIDDEN_DIM];             // 2048 floats  = 8192B
    for (int t = threadIdx.x; t < EDGE_DIM * NODE_DIM * HIDDEN_DIM; t += blockDim.x)
        wS[t] = w_nn[t];
    for (int t = threadIdx.x; t < NODE_DIM * HIDDEN_DIM; t += blockDim.x)
        bS[t] = b_nn[t];
    __syncthreads();

    const int lane   = threadIdx.x & 63;
    const int wave   = (blockIdx.x * blockDim.x + threadIdx.x) >> 6;
    const int nwaves = (gridDim.x * blockDim.x) >> 6;
    const int* __restrict__ srcs = ei;
    const int* __restrict__ dsts = ei + NUM_EDGES;

    for (int e0 = wave * MB; e0 < NUM_EDGES; e0 += nwaves * MB) {
        // NUM_EDGES % MB == 0, no tail
        int   src[MB], dst[MB];
        float ev[MB][EDGE_DIM];
        float acc[MB];
        #pragma unroll
        for (int m = 0; m < MB; ++m) {
            src[m] = srcs[e0 + m];
            dst[m] = dsts[e0 + m];
            acc[m] = 0.f;
            #pragma unroll
            for (int k = 0; k < EDGE_DIM; ++k)
                ev[m][k] = ea[(e0 + m) * EDGE_DIM + k];
        }

        #pragma unroll 4
        for (int i = 0; i < NODE_DIM; ++i) {
            float wv[EDGE_DIM];
            #pragma unroll
            for (int k = 0; k < EDGE_DIM; ++k)
                wv[k] = wS[k * (NODE_DIM * HIDDEN_DIM) + i * HIDDEN_DIM + lane];
            const float bb = bS[i * HIDDEN_DIM + lane];
            #pragma unroll
            for (int m = 0; m < MB; ++m) {
                float t = bb;
                #pragma unroll
                for (int k = 0; k < EDGE_DIM; ++k)
                    t = fmaf(ev[m][k], wv[k], t);
                t = fmaxf(t, 0.f);
                acc[m] = fmaf(x[src[m] * NODE_DIM + i], t, acc[m]);
            }
        }

        #pragma unroll
        for (int m = 0; m < MB; ++m)
            atomicAdd(&agg[dst[m] * HIDDEN_DIM + lane], acc[m]);
    }
}

// ---------------------------------------------------------------------------
// K_C: edge classifier.
//   h = relu(agg)   (applied on read)
//   z[o] = relu(b_e1[o] + sum_j h[src][j]*w1[j][o] + h[dst][j]*w1[64+j][o]
//                       + sum_k e[k]*w1[128+k][o])
//   out[c] = b_e2[c] + sum_o z[o]*w_e2[o][c]    (64-lane shfl reduction)
// one wave handles M=4 edges, lane = hidden channel o.
// ---------------------------------------------------------------------------
#define ME 4
#define EREP (2 * HIDDEN_DIM + EDGE_DIM)  // 135
__global__ __launch_bounds__(256) void k_edge(const int* __restrict__ ei,
                                              const float* __restrict__ ea,
                                              const float* __restrict__ agg,
                                              const float* __restrict__ w_e1,
                                              const float* __restrict__ b_e1,
                                              const float* __restrict__ w_e2,
                                              const float* __restrict__ b_e2,
                                              float* __restrict__ out) {
    __shared__ float w1[EREP * 64];   // 34560B
    __shared__ float b1[64];
    __shared__ float w2[64 * 2];
    __shared__ float b2[2];
    for (int t = threadIdx.x; t < EREP * 64; t += blockDim.x) w1[t] = w_e1[t];
    if (threadIdx.x < 64)  b1[threadIdx.x] = b_e1[threadIdx.x];
    if (threadIdx.x < 128) w2[threadIdx.x] = w_e2[threadIdx.x];
    if (threadIdx.x < 2)   b2[threadIdx.x] = b_e2[threadIdx.x];
    __syncthreads();

    const int lane   = threadIdx.x & 63;
    const int wave   = (blockIdx.x * blockDim.x + threadIdx.x) >> 6;
    const int nwaves = (gridDim.x * blockDim.x) >> 6;
    const int* __restrict__ srcs = ei;
    const int* __restrict__ dsts = ei + NUM_EDGES;

    for (int e0 = wave * ME; e0 < NUM_EDGES; e0 += nwaves * ME) {
        int   src[ME], dst[ME];
        float acc[ME];
        #pragma unroll
        for (int m = 0; m < ME; ++m) {
            src[m] = srcs[e0 + m];
            dst[m] = dsts[e0 + m];
            acc[m] = b1[lane];
        }

        #pragma unroll 8
        for (int j = 0; j < HIDDEN_DIM; ++j) {
            const float ws = w1[j * 64 + lane];
            const float wd = w1[(HIDDEN_DIM + j) * 64 + lane];
            #pragma unroll
            for (int m = 0; m < ME; ++m) {
                const float hs = fmaxf(agg[src[m] * HIDDEN_DIM + j], 0.f);
                const float hd = fmaxf(agg[dst[m] * HIDDEN_DIM + j], 0.f);
                acc[m] = fmaf(hs, ws, acc[m]);
                acc[m] = fmaf(hd, wd, acc[m]);
            }
        }
        #pragma unroll
        for (int k = 0; k < EDGE_DIM; ++k) {
            const float we = w1[(2 * HIDDEN_DIM + k) * 64 + lane];
            #pragma unroll
            for (int m = 0; m < ME; ++m)
                acc[m] = fmaf(ea[(e0 + m) * EDGE_DIM + k], we, acc[m]);
        }

        #pragma unroll
        for (int m = 0; m < ME; ++m) {
            const float z  = fmaxf(acc[m], 0.f);
            float o0 = z * w2[lane * 2 + 0];
            float o1 = z * w2[lane * 2 + 1];
            #pragma unroll
            for (int off = 32; off; off >>= 1) {
                o0 += __shfl_xor(o0, off);
                o1 += __shfl_xor(o1, off);
            }
            if (lane == 0) {
                out[(e0 + m) * 2 + 0] = o0 + b2[0];
                out[(e0 + m) * 2 + 1] = o1 + b2[1];
            }
        }
    }
}

// ---------------------------------------------------------------------------
extern "C" void kernel_launch(void* const* d_in, const int* in_sizes, int n_in,
                              void* d_out, int out_size, void* d_ws, size_t ws_size,
                              hipStream_t stream) {
    const int*   ei        = (const int*)d_in[0];
    const float* edge_attr = (const float*)d_in[1];
    const float* node_emb  = (const float*)d_in[2];
    const float* w_nn      = (const float*)d_in[3];
    const float* b_nn      = (const float*)d_in[4];
    const float* root_w    = (const float*)d_in[5];
    const float* conv_bias = (const float*)d_in[6];
    const float* w_e1      = (const float*)d_in[7];
    const float* b_e1      = (const float*)d_in[8];
    const float* w_e2      = (const float*)d_in[9];
    const float* b_e2      = (const float*)d_in[10];
    float*       out       = (float*)d_out;
    float*       agg       = (float*)d_ws;   // [NUM_NODES, 64] f32 = 12.8 MB

    // K_A: agg = x @ root_w + conv_bias  (fully overwrites ws region each call)
    k_init<<<512, 256, 0, stream>>>(node_emb, root_w, conv_bias, agg);
    // K_B: fused edge-MLP + per-edge matmul + scatter-add
    k_msg<<<512, 512, 0, stream>>>(ei, edge_attr, node_emb, w_nn, b_nn, agg);
    // K_C: edge classifier (relu(agg) applied on read)
    k_edge<<<1024, 256, 0, stream>>>(ei, edge_attr, agg, w_e1, b_e1, w_e2, b_e2, out);
}

// Round 2
// 266.036 us; speedup vs baseline: 1.5331x; 1.5331x over previous
//
#include <hip/hip_runtime.h>
#include <hip/hip_bf16.h>

#define NUM_NODES 50000
#define NODE_DIM 32
#define EDGE_DIM 7
#define HIDDEN_DIM 64
#define NUM_EDGES 200000

// ---------------------------------------------------------------------------
// K_A: agg[n][o] = conv_bias[o] + sum_i x[n][i] * root_w[i][o]
// one wave per node, lane = output channel o (64 == wave size)
// ---------------------------------------------------------------------------
__global__ __launch_bounds__(256) void k_init(const float* __restrict__ x,
                                              const float* __restrict__ root_w,
                                              const float* __restrict__ conv_bias,
                                              float* __restrict__ agg) {
    __shared__ float rw[NODE_DIM * HIDDEN_DIM];
    __shared__ float cb[HIDDEN_DIM];
    for (int t = threadIdx.x; t < NODE_DIM * HIDDEN_DIM; t += blockDim.x) rw[t] = root_w[t];
    if (threadIdx.x < HIDDEN_DIM) cb[threadIdx.x] = conv_bias[threadIdx.x];
    __syncthreads();

    const int lane   = threadIdx.x & 63;
    const int wave   = (blockIdx.x * blockDim.x + threadIdx.x) >> 6;
    const int nwaves = (gridDim.x * blockDim.x) >> 6;

    for (int n = wave; n < NUM_NODES; n += nwaves) {
        float acc = cb[lane];
        const float* xr = x + n * NODE_DIM;
        #pragma unroll
        for (int i = 0; i < NODE_DIM; ++i)
            acc = fmaf(xr[i], rw[i * HIDDEN_DIM + lane], acc);
        agg[n * HIDDEN_DIM + lane] = acc;
    }
}

// ---------------------------------------------------------------------------
// K_T: transpose w_e1 [135][64] -> w1t [64][136] (row-contiguous per output
// channel o; col 135 zero-padded so a row is exactly 34 float4s).
// ---------------------------------------------------------------------------
__global__ __launch_bounds__(256) void k_transpose(const float* __restrict__ w_e1,
                                                   float* __restrict__ w1t) {
    int t = blockIdx.x * blockDim.x + threadIdx.x;
    if (t < 64 * 136) {
        int o = t / 136, j = t % 136;
        w1t[t] = (j < 135) ? w_e1[j * 64 + o] : 0.f;
    }
}

// ---------------------------------------------------------------------------
// K_B: fused NNConv message + scatter.
//   w_edge[i][o] = relu(b_nn[i*64+o] + sum_k e[k]*w_nn[k][i*64+o])
//   msg[o]       = sum_i x[src][i] * w_edge[i][o]
//   atomicAdd(agg[dst][o], msg[o])
// one wave handles M=4 edges, lane = output channel o.
// x rows staged per-wave in LDS (coalesced load, broadcast read) to kill the
// wave-uniform global gather latency of round 1.
// ---------------------------------------------------------------------------
#define MB 4
__global__ __launch_bounds__(512) void k_msg(const int* __restrict__ ei,
                                             const float* __restrict__ ea,
                                             const float* __restrict__ x,
                                             const float* __restrict__ w_nn,
                                             const float* __restrict__ b_nn,
                                             float* __restrict__ agg) {
    __shared__ float wS[EDGE_DIM * NODE_DIM * HIDDEN_DIM];  // 57344B
    __shared__ float bS[NODE_DIM * HIDDEN_DIM];             // 8192B
    __shared__ float xS[8][MB][NODE_DIM];                   // 4096B (per-wave slots)
    for (int t = threadIdx.x; t < EDGE_DIM * NODE_DIM * HIDDEN_DIM; t += blockDim.x)
        wS[t] = w_nn[t];
    for (int t = threadIdx.x; t < NODE_DIM * HIDDEN_DIM; t += blockDim.x)
        bS[t] = b_nn[t];
    __syncthreads();

    const int lane   = threadIdx.x & 63;
    const int wslot  = threadIdx.x >> 6;
    const int wave   = (blockIdx.x * blockDim.x + threadIdx.x) >> 6;
    const int nwaves = (gridDim.x * blockDim.x) >> 6;
    const int* __restrict__ srcs = ei;
    const int* __restrict__ dsts = ei + NUM_EDGES;

    for (int e0 = wave * MB; e0 < NUM_EDGES; e0 += nwaves * MB) {
        // NUM_EDGES % MB == 0, no tail
        int   dst[MB];
        float ev[MB][EDGE_DIM];
        float acc[MB];
        #pragma unroll
        for (int m = 0; m < MB; ++m) {
            dst[m] = dsts[e0 + m];
            acc[m] = 0.f;
            #pragma unroll
            for (int k = 0; k < EDGE_DIM; ++k)
                ev[m][k] = ea[(e0 + m) * EDGE_DIM + k];
        }
        // stage x[src[0..3]] rows: lanes 0..31 handle m = {0,2}? -> m = rep*2 + (lane>>5)
        {
            const int ii = lane & 31;
            #pragma unroll
            for (int rep = 0; rep < 2; ++rep) {
                const int m = rep * 2 + (lane >> 5);
                const int s = srcs[e0 + m];
                xS[wslot][m][ii] = x[s * NODE_DIM + ii];
            }
        }
        // wave-coherent: LDS write->read within one wave; compiler inserts lgkmcnt.

        #pragma unroll 4
        for (int i = 0; i < NODE_DIM; ++i) {
            float wv[EDGE_DIM];
            #pragma unroll
            for (int k = 0; k < EDGE_DIM; ++k)
                wv[k] = wS[k * (NODE_DIM * HIDDEN_DIM) + i * HIDDEN_DIM + lane];
            const float bb = bS[i * HIDDEN_DIM + lane];
            #pragma unroll
            for (int m = 0; m < MB; ++m) {
                float t = bb;
                #pragma unroll
                for (int k = 0; k < EDGE_DIM; ++k)
                    t = fmaf(ev[m][k], wv[k], t);
                t = fmaxf(t, 0.f);
                acc[m] = fmaf(xS[wslot][m][i], t, acc[m]);
            }
        }

        #pragma unroll
        for (int m = 0; m < MB; ++m)
            atomicAdd(&agg[dst[m] * HIDDEN_DIM + lane], acc[m]);
    }
}

// ---------------------------------------------------------------------------
// K_C v2: edge classifier, lane = edge (64 edges per wave).
//   Each lane gathers its own h[src], h[dst] rows (relu on read) into 128
//   VGPRs as float4s (statically indexed), then loops o = 0..63 reading the
//   transposed weight row w1t[o][0..135] as 34 uniform float4 loads.
//   z = relu(dot) ; out += z * w_e2[o][:]
// ---------------------------------------------------------------------------
__global__ __launch_bounds__(256) void k_edge2(const int* __restrict__ ei,
                                               const float* __restrict__ ea,
                                               const float* __restrict__ agg,
                                               const float* __restrict__ w1t,
                                               const float* __restrict__ b_e1,
                                               const float* __restrict__ w_e2,
                                               const float* __restrict__ b_e2,
                                               float* __restrict__ out) {
    const int lane = threadIdx.x & 63;
    const int wave = (blockIdx.x * blockDim.x + threadIdx.x) >> 6;
    if (wave >= NUM_EDGES / 64) return;   // wave-uniform exit (200000 % 64 == 0)
    const int e   = wave * 64 + lane;
    const int src = ei[e];
    const int dst = ei[NUM_EDGES + e];

    // edge attr (ev[7] = 0 pairs with w1t's zero pad)
    float ev[8];
    #pragma unroll
    for (int k = 0; k < EDGE_DIM; ++k) ev[k] = ea[e * EDGE_DIM + k];
    ev[7] = 0.f;

    // gather + relu h rows into registers
    float4 hs[16], hd[16];
    const float4* ps = (const float4*)(agg + src * HIDDEN_DIM);
    const float4* pd = (const float4*)(agg + dst * HIDDEN_DIM);
    #pragma unroll
    for (int q = 0; q < 16; ++q) { hs[q] = ps[q]; hd[q] = pd[q]; }
    #pragma unroll
    for (int q = 0; q < 16; ++q) {
        hs[q].x = fmaxf(hs[q].x, 0.f); hs[q].y = fmaxf(hs[q].y, 0.f);
        hs[q].z = fmaxf(hs[q].z, 0.f); hs[q].w = fmaxf(hs[q].w, 0.f);
        hd[q].x = fmaxf(hd[q].x, 0.f); hd[q].y = fmaxf(hd[q].y, 0.f);
        hd[q].z = fmaxf(hd[q].z, 0.f); hd[q].w = fmaxf(hd[q].w, 0.f);
    }

    float o0 = b_e2[0], o1 = b_e2[1];

    for (int o = 0; o < HIDDEN_DIM; ++o) {
        const float4* wr = (const float4*)(w1t + o * 136);
        float t0 = b_e1[o], t1 = 0.f, t2 = 0.f, t3 = 0.f;
        // src part: w1t row floats [0..63]
        #pragma unroll
        for (int q = 0; q < 16; q += 4) {
            float4 w0 = wr[q], w1 = wr[q + 1], w2 = wr[q + 2], w3 = wr[q + 3];
            t0 = fmaf(hs[q].x,     w0.x, t0); t0 = fmaf(hs[q].y,     w0.y, t0);
            t0 = fmaf(hs[q].z,     w0.z, t0); t0 = fmaf(hs[q].w,     w0.w, t0);
            t1 = fmaf(hs[q + 1].x, w1.x, t1); t1 = fmaf(hs[q + 1].y, w1.y, t1);
            t1 = fmaf(hs[q + 1].z, w1.z, t1); t1 = fmaf(hs[q + 1].w, w1.w, t1);
            t2 = fmaf(hs[q + 2].x, w2.x, t2); t2 = fmaf(hs[q + 2].y, w2.y, t2);
            t2 = fmaf(hs[q + 2].z, w2.z, t2); t2 = fmaf(hs[q + 2].w, w2.w, t2);
            t3 = fmaf(hs[q + 3].x, w3.x, t3); t3 = fmaf(hs[q + 3].y, w3.y, t3);
            t3 = fmaf(hs[q + 3].z, w3.z, t3); t3 = fmaf(hs[q + 3].w, w3.w, t3);
        }
        // dst part: w1t row floats [64..127]
        #pragma unroll
        for (int q = 0; q < 16; q += 4) {
            float4 w0 = wr[16 + q], w1 = wr[17 + q], w2 = wr[18 + q], w3 = wr[19 + q];
            t0 = fmaf(hd[q].x,     w0.x, t0); t0 = fmaf(hd[q].y,     w0.y, t0);
            t0 = fmaf(hd[q].z,     w0.z, t0); t0 = fmaf(hd[q].w,     w0.w, t0);
            t1 = fmaf(hd[q + 1].x, w1.x, t1); t1 = fmaf(hd[q + 1].y, w1.y, t1);
            t1 = fmaf(hd[q + 1].z, w1.z, t1); t1 = fmaf(hd[q + 1].w, w1.w, t1);
            t2 = fmaf(hd[q + 2].x, w2.x, t2); t2 = fmaf(hd[q + 2].y, w2.y, t2);
            t2 = fmaf(hd[q + 2].z, w2.z, t2); t2 = fmaf(hd[q + 2].w, w2.w, t2);
            t3 = fmaf(hd[q + 3].x, w3.x, t3); t3 = fmaf(hd[q + 3].y, w3.y, t3);
            t3 = fmaf(hd[q + 3].z, w3.z, t3); t3 = fmaf(hd[q + 3].w, w3.w, t3);
        }
        // edge-attr part: w1t row floats [128..135] (last one is the zero pad)
        {
            float4 w0 = wr[32], w1 = wr[33];
            t0 = fmaf(ev[0], w0.x, t0); t1 = fmaf(ev[1], w0.y, t1);
            t2 = fmaf(ev[2], w0.z, t2); t3 = fmaf(ev[3], w0.w, t3);
            t0 = fmaf(ev[4], w1.x, t0); t1 = fmaf(ev[5], w1.y, t1);
            t2 = fmaf(ev[6], w1.z, t2); t3 = fmaf(ev[7], w1.w, t3);
        }
        const float z = fmaxf((t0 + t1) + (t2 + t3), 0.f);
        o0 = fmaf(z, w_e2[o * 2 + 0], o0);
        o1 = fmaf(z, w_e2[o * 2 + 1], o1);
    }

    out[e * 2 + 0] = o0;
    out[e * 2 + 1] = o1;
}

// ---------------------------------------------------------------------------
extern "C" void kernel_launch(void* const* d_in, const int* in_sizes, int n_in,
                              void* d_out, int out_size, void* d_ws, size_t ws_size,
                              hipStream_t stream) {
    const int*   ei        = (const int*)d_in[0];
    const float* edge_attr = (const float*)d_in[1];
    const float* node_emb  = (const float*)d_in[2];
    const float* w_nn      = (const float*)d_in[3];
    const float* b_nn      = (const float*)d_in[4];
    const float* root_w    = (const float*)d_in[5];
    const float* conv_bias = (const float*)d_in[6];
    const float* w_e1      = (const float*)d_in[7];
    const float* b_e1      = (const float*)d_in[8];
    const float* w_e2      = (const float*)d_in[9];
    const float* b_e2      = (const float*)d_in[10];
    float*       out       = (float*)d_out;
    float*       agg       = (float*)d_ws;                       // [N,64] f32 = 12.8 MB
    float*       w1t       = (float*)((char*)d_ws + (size_t)NUM_NODES * HIDDEN_DIM * 4); // [64][136]

    // K_T: transpose classifier weight (w1t fully written incl. pad)
    k_transpose<<<(64 * 136 + 255) / 256, 256, 0, stream>>>(w_e1, w1t);
    // K_A: agg = x @ root_w + conv_bias  (fully overwrites region each call)
    k_init<<<512, 256, 0, stream>>>(node_emb, root_w, conv_bias, agg);
    // K_B: fused edge-MLP + per-edge matmul + scatter-add
    k_msg<<<512, 512, 0, stream>>>(ei, edge_attr, node_emb, w_nn, b_nn, agg);
    // K_C: edge classifier, lane = edge
    {
        const int nwaves = NUM_EDGES / 64;          // 3125
        const int blocks = (nwaves + 3) / 4;        // 782 blocks of 4 waves
        k_edge2<<<blocks, 256, 0, stream>>>(ei, edge_attr, agg, w1t, b_e1, w_e2, b_e2, out);
    }
}

// Round 3
// 246.682 us; speedup vs baseline: 1.6533x; 1.0785x over previous
//
#include <hip/hip_runtime.h>
#include <hip/hip_bf16.h>

#define NUM_NODES 50000
#define NODE_DIM 32
#define EDGE_DIM 7
#define HIDDEN_DIM 64
#define NUM_EDGES 200000

// ---------------------------------------------------------------------------
// K_P: build w1te [64][136] in ws: w1te[o][j] = w_e1[j][o] for j<135,
//      w1te[o][135] = b_e1[o]  (bias folded; classifier uses ev[7]=1.0).
// Same ws footprint as round 2 (agg 12.8MB + 34.8KB) — proven to fit.
// ---------------------------------------------------------------------------
__global__ __launch_bounds__(256) void k_prep(const float* __restrict__ w_e1,
                                              const float* __restrict__ b_e1,
                                              float* __restrict__ w1te) {
    int u = blockIdx.x * blockDim.x + threadIdx.x;
    if (u < 64 * 136) {
        int o = u / 136, j = u % 136;
        w1te[u] = (j < 135) ? w_e1[j * 64 + o] : b_e1[o];
    }
}

// ---------------------------------------------------------------------------
// K_A: agg[n][o] = conv_bias[o] + sum_i x[n][i] * root_w[i][o]
// block = 256 threads = 4 waves; each block stages 128 x-rows into LDS
// (coalesced float4), each wave computes 32 nodes with lane = o.
// ---------------------------------------------------------------------------
__global__ __launch_bounds__(256) void k_init2(const float* __restrict__ x,
                                               const float* __restrict__ root_w,
                                               const float* __restrict__ conv_bias,
                                               float* __restrict__ agg) {
    __shared__ float rw[NODE_DIM * HIDDEN_DIM];   // 8KB
    __shared__ float cb[HIDDEN_DIM];
    __shared__ float xS[128 * NODE_DIM];          // 16KB
    for (int t = threadIdx.x; t < NODE_DIM * HIDDEN_DIM; t += 256) rw[t] = root_w[t];
    if (threadIdx.x < HIDDEN_DIM) cb[threadIdx.x] = conv_bias[threadIdx.x];
    const int nb = blockIdx.x * 128;
    {
        const float4* xg = (const float4*)x;
        float4* xs4 = (float4*)xS;
        #pragma unroll
        for (int r = 0; r < 4; ++r) {
            int t = r * 256 + threadIdx.x;                // 1024 float4s per block
            int gi = nb * (NODE_DIM / 4) + t;
            xs4[t] = (gi < NUM_NODES * (NODE_DIM / 4)) ? xg[gi] : make_float4(0.f, 0.f, 0.f, 0.f);
        }
    }
    __syncthreads();
    const int lane = threadIdx.x & 63;
    const int w    = threadIdx.x >> 6;
    for (int r = 0; r < 32; ++r) {
        const int n = nb + w * 32 + r;
        if (n >= NUM_NODES) break;                         // wave-uniform
        float acc = cb[lane];
        const float* xr = &xS[(w * 32 + r) * NODE_DIM];
        #pragma unroll
        for (int i = 0; i < NODE_DIM; ++i)
            acc = fmaf(xr[i], rw[i * HIDDEN_DIM + lane], acc);
        agg[n * HIDDEN_DIM + lane] = acc;
    }
}

// ---------------------------------------------------------------------------
// K_B: fused NNConv message + scatter.
// LDS holds w_nn repacked as two [32][64] float4 planes:
//   wAs[i][o] = {w_nn[0..3][i*64+o]}, wBs[i][o] = {w_nn[4..6][i*64+o], b_nn}
// -> 2 conflict-free ds_read_b128 per i (lane stride 16B, contiguous 1KB).
// Edge attrs staged per-group into LDS (coalesced), read back as broadcasts.
// ---------------------------------------------------------------------------
#define MB 4
__global__ __launch_bounds__(512) void k_msg(const int* __restrict__ ei,
                                             const float* __restrict__ ea,
                                             const float* __restrict__ x,
                                             const float* __restrict__ w_nn,
                                             const float* __restrict__ b_nn,
                                             float* __restrict__ agg) {
    __shared__ float4 wAs[NODE_DIM * HIDDEN_DIM / 4 * 4]; // [32][64] float4 = 32KB
    __shared__ float4 wBs[NODE_DIM * HIDDEN_DIM / 4 * 4]; // 32KB
    __shared__ float  xS[8][MB * NODE_DIM];               // 4KB
    __shared__ float  eS[8][MB][8];                       // 1KB
    for (int t = threadIdx.x; t < NODE_DIM * HIDDEN_DIM; t += 512) {
        wAs[t] = make_float4(w_nn[t],            w_nn[2048 + t],
                             w_nn[2 * 2048 + t], w_nn[3 * 2048 + t]);
        wBs[t] = make_float4(w_nn[4 * 2048 + t], w_nn[5 * 2048 + t],
                             w_nn[6 * 2048 + t], b_nn[t]);
    }
    __syncthreads();

    const int lane   = threadIdx.x & 63;
    const int ws     = threadIdx.x >> 6;
    const int wave   = (blockIdx.x * blockDim.x + threadIdx.x) >> 6;
    const int nwaves = (gridDim.x * blockDim.x) >> 6;
    const int* __restrict__ srcs = ei;
    const int* __restrict__ dsts = ei + NUM_EDGES;
    const int em = lane / EDGE_DIM, ek = lane % EDGE_DIM;  // hoisted

    for (int e0 = wave * MB; e0 < NUM_EDGES; e0 += nwaves * MB) {
        // stage x[src] rows (coalesced 128B per row) + edge attrs (28 floats)
        {
            const int ii = lane & 31;
            #pragma unroll
            for (int rep = 0; rep < 2; ++rep) {
                const int m = rep * 2 + (lane >> 5);
                xS[ws][m * NODE_DIM + ii] = x[srcs[e0 + m] * NODE_DIM + ii];
            }
            if (lane < MB * EDGE_DIM) eS[ws][em][ek] = ea[e0 * EDGE_DIM + lane];
        }
        // wave-coherent LDS write->read; compiler inserts lgkmcnt waits.
        int    dst[MB];
        float4 ev0[MB], ev1[MB];
        float  acc[MB];
        #pragma unroll
        for (int m = 0; m < MB; ++m) {
            dst[m] = dsts[e0 + m];
            const float4* ep = (const float4*)&eS[ws][m][0];
            ev0[m] = ep[0]; ev1[m] = ep[1];   // ev1[m].w unused (never written)
            acc[m] = 0.f;
        }

        #pragma unroll 8
        for (int i = 0; i < NODE_DIM; ++i) {
            const float4 a = wAs[i * HIDDEN_DIM + lane];
            const float4 b = wBs[i * HIDDEN_DIM + lane];
            #pragma unroll
            for (int m = 0; m < MB; ++m) {
                float t = b.w;                          // bias
                t = fmaf(ev0[m].x, a.x, t); t = fmaf(ev0[m].y, a.y, t);
                t = fmaf(ev0[m].z, a.z, t); t = fmaf(ev0[m].w, a.w, t);
                t = fmaf(ev1[m].x, b.x, t); t = fmaf(ev1[m].y, b.y, t);
                t = fmaf(ev1[m].z, b.z, t);
                t = fmaxf(t, 0.f);
                acc[m] = fmaf(xS[ws][m * NODE_DIM + i], t, acc[m]);
            }
        }

        #pragma unroll
        for (int m = 0; m < MB; ++m)
            atomicAdd(&agg[dst[m] * HIDDEN_DIM + lane], acc[m]);
    }
}

// ---------------------------------------------------------------------------
// K_C: edge classifier, lane = edge; w1te staged in LDS (34.8KB), inner loop
// reads weight rows as uniform ds_read_b128 broadcasts (conflict-free).
// bias b_e1 folded at col 135 (ev[7] = 1.0); b_e2/w_e2 also in LDS.
// ---------------------------------------------------------------------------
__global__ __launch_bounds__(256) void k_edge2(const int* __restrict__ ei,
                                               const float* __restrict__ ea,
                                               const float* __restrict__ agg,
                                               const float* __restrict__ w1te,
                                               const float* __restrict__ w_e2,
                                               const float* __restrict__ b_e2,
                                               float* __restrict__ out) {
    __shared__ float w1S[64 * 136];   // 34816B
    __shared__ float w2S[128];
    __shared__ float b2S[2];
    {
        const float4* g4 = (const float4*)w1te;
        float4* s4 = (float4*)w1S;
        for (int t = threadIdx.x; t < 64 * 136 / 4; t += 256) s4[t] = g4[t];
        if (threadIdx.x < 128) w2S[threadIdx.x] = w_e2[threadIdx.x];
        if (threadIdx.x < 2)   b2S[threadIdx.x] = b_e2[threadIdx.x];
    }
    __syncthreads();

    const int lane = threadIdx.x & 63;
    const int wave = (blockIdx.x * blockDim.x + threadIdx.x) >> 6;
    if (wave < NUM_EDGES / 64) {                   // 200000 % 64 == 0
        const int e   = wave * 64 + lane;
        const int src = ei[e];
        const int dst = ei[NUM_EDGES + e];

        float ev[8];
        #pragma unroll
        for (int k = 0; k < EDGE_DIM; ++k) ev[k] = ea[e * EDGE_DIM + k];
        ev[7] = 1.0f;                               // pairs with folded bias

        float4 hs[16], hd[16];
        const float4* ps = (const float4*)(agg + src * HIDDEN_DIM);
        const float4* pd = (const float4*)(agg + dst * HIDDEN_DIM);
        #pragma unroll
        for (int q = 0; q < 16; ++q) { hs[q] = ps[q]; hd[q] = pd[q]; }
        #pragma unroll
        for (int q = 0; q < 16; ++q) {
            hs[q].x = fmaxf(hs[q].x, 0.f); hs[q].y = fmaxf(hs[q].y, 0.f);
            hs[q].z = fmaxf(hs[q].z, 0.f); hs[q].w = fmaxf(hs[q].w, 0.f);
            hd[q].x = fmaxf(hd[q].x, 0.f); hd[q].y = fmaxf(hd[q].y, 0.f);
            hd[q].z = fmaxf(hd[q].z, 0.f); hd[q].w = fmaxf(hd[q].w, 0.f);
        }

        float o0 = b2S[0], o1 = b2S[1];

        for (int o = 0; o < HIDDEN_DIM; ++o) {
            const float4* wr = (const float4*)&w1S[o * 136];
            float t0 = 0.f, t1 = 0.f, t2 = 0.f, t3 = 0.f;
            #pragma unroll
            for (int q = 0; q < 16; q += 4) {
                float4 w0 = wr[q], w1 = wr[q + 1], w2 = wr[q + 2], w3 = wr[q + 3];
                t0 = fmaf(hs[q].x,     w0.x, t0); t0 = fmaf(hs[q].y,     w0.y, t0);
                t0 = fmaf(hs[q].z,     w0.z, t0); t0 = fmaf(hs[q].w,     w0.w, t0);
                t1 = fmaf(hs[q + 1].x, w1.x, t1); t1 = fmaf(hs[q + 1].y, w1.y, t1);
                t1 = fmaf(hs[q + 1].z, w1.z, t1); t1 = fmaf(hs[q + 1].w, w1.w, t1);
                t2 = fmaf(hs[q + 2].x, w2.x, t2); t2 = fmaf(hs[q + 2].y, w2.y, t2);
                t2 = fmaf(hs[q + 2].z, w2.z, t2); t2 = fmaf(hs[q + 2].w, w2.w, t2);
                t3 = fmaf(hs[q + 3].x, w3.x, t3); t3 = fmaf(hs[q + 3].y, w3.y, t3);
                t3 = fmaf(hs[q + 3].z, w3.z, t3); t3 = fmaf(hs[q + 3].w, w3.w, t3);
            }
            #pragma unroll
            for (int q = 0; q < 16; q += 4) {
                float4 w0 = wr[16 + q], w1 = wr[17 + q], w2 = wr[18 + q], w3 = wr[19 + q];
                t0 = fmaf(hd[q].x,     w0.x, t0); t0 = fmaf(hd[q].y,     w0.y, t0);
                t0 = fmaf(hd[q].z,     w0.z, t0); t0 = fmaf(hd[q].w,     w0.w, t0);
                t1 = fmaf(hd[q + 1].x, w1.x, t1); t1 = fmaf(hd[q + 1].y, w1.y, t1);
                t1 = fmaf(hd[q + 1].z, w1.z, t1); t1 = fmaf(hd[q + 1].w, w1.w, t1);
                t2 = fmaf(hd[q + 2].x, w2.x, t2); t2 = fmaf(hd[q + 2].y, w2.y, t2);
                t2 = fmaf(hd[q + 2].z, w2.z, t2); t2 = fmaf(hd[q + 2].w, w2.w, t2);
                t3 = fmaf(hd[q + 3].x, w3.x, t3); t3 = fmaf(hd[q + 3].y, w3.y, t3);
                t3 = fmaf(hd[q + 3].z, w3.z, t3); t3 = fmaf(hd[q + 3].w, w3.w, t3);
            }
            {
                float4 w0 = wr[32], w1 = wr[33];  // ea part + folded bias
                t0 = fmaf(ev[0], w0.x, t0); t1 = fmaf(ev[1], w0.y, t1);
                t2 = fmaf(ev[2], w0.z, t2); t3 = fmaf(ev[3], w0.w, t3);
                t0 = fmaf(ev[4], w1.x, t0); t1 = fmaf(ev[5], w1.y, t1);
                t2 = fmaf(ev[6], w1.z, t2); t3 = fmaf(ev[7], w1.w, t3);
            }
            const float z = fmaxf((t0 + t1) + (t2 + t3), 0.f);
            o0 = fmaf(z, w2S[o * 2 + 0], o0);
            o1 = fmaf(z, w2S[o * 2 + 1], o1);
        }

        float2 r; r.x = o0; r.y = o1;
        ((float2*)out)[e] = r;
    }
}

// ---------------------------------------------------------------------------
extern "C" void kernel_launch(void* const* d_in, const int* in_sizes, int n_in,
                              void* d_out, int out_size, void* d_ws, size_t ws_size,
                              hipStream_t stream) {
    const int*   ei        = (const int*)d_in[0];
    const float* edge_attr = (const float*)d_in[1];
    const float* node_emb  = (const float*)d_in[2];
    const float* w_nn      = (const float*)d_in[3];
    const float* b_nn      = (const float*)d_in[4];
    const float* root_w    = (const float*)d_in[5];
    const float* conv_bias = (const float*)d_in[6];
    const float* w_e1      = (const float*)d_in[7];
    const float* b_e1      = (const float*)d_in[8];
    const float* w_e2      = (const float*)d_in[9];
    const float* b_e2      = (const float*)d_in[10];
    float*       out       = (float*)d_out;
    float*       agg       = (float*)d_ws;  // [N,64] f32 = 12.8 MB
    float*       w1te      = (float*)((char*)d_ws + (size_t)NUM_NODES * HIDDEN_DIM * 4); // [64][136]

    // K_P: transposed classifier weight with folded bias
    k_prep<<<(64 * 136 + 255) / 256, 256, 0, stream>>>(w_e1, b_e1, w1te);
    // K_A: agg = x @ root_w + conv_bias (fully rewrites region each call)
    k_init2<<<(NUM_NODES + 127) / 128, 256, 0, stream>>>(node_emb, root_w, conv_bias, agg);
    // K_B: fused edge-MLP + per-edge matmul + scatter-add
    k_msg<<<512, 512, 0, stream>>>(ei, edge_attr, node_emb, w_nn, b_nn, agg);
    // K_C: edge classifier
    k_edge2<<<(NUM_EDGES / 64 + 3) / 4, 256, 0, stream>>>(ei, edge_attr, agg, w1te, w_e2, b_e2, out);
}

// Round 4
// 154.296 us; speedup vs baseline: 2.6433x; 1.5988x over previous
//
#include <hip/hip_runtime.h>
#include <hip/hip_bf16.h>

#define NUM_NODES 50000
#define NODE_DIM 32
#define EDGE_DIM 7
#define HIDDEN_DIM 64
#define NUM_EDGES 200000

typedef __attribute__((ext_vector_type(8))) short bf16x8;
typedef __attribute__((ext_vector_type(4))) float f32x4;

__device__ inline unsigned f2bf(float f) {
    union { float f; unsigned u; } x; x.f = f;
    return (x.u + 0x7FFFu + ((x.u >> 16) & 1u)) >> 16;   // RNE
}
__device__ inline unsigned pack2bf(float a, float b) {
    return f2bf(a) | (f2bf(b) << 16);
}

// ---------------------------------------------------------------------------
// K_P: build per-lane B fragments for the classifier GEMM in ws.
// W1p[k][o]: k<135 -> w_e1[k][o]; k==135 -> b_e1[o]; 136..159 -> 0.
// bfrag layout [kstep][ntile][lane][j] (j fastest), element =
//   W1p[kstep*32 + (lane>>4)*8 + j][ntile*16 + (lane&15)]  as bf16.
// ---------------------------------------------------------------------------
__global__ __launch_bounds__(256) void k_prep(const float* __restrict__ w_e1,
                                              const float* __restrict__ b_e1,
                                              ushort* __restrict__ bfrag) {
    int u = blockIdx.x * blockDim.x + threadIdx.x;
    if (u < 5 * 4 * 64 * 8) {
        int j     = u & 7;
        int lane  = (u >> 3) & 63;
        int ntile = (u >> 9) & 3;
        int kstep = u >> 11;
        int k = kstep * 32 + (lane >> 4) * 8 + j;
        int o = ntile * 16 + (lane & 15);
        float v = (k < 135) ? w_e1[k * 64 + o] : ((k == 135) ? b_e1[o] : 0.f);
        bfrag[u] = (ushort)f2bf(v);
    }
}

// ---------------------------------------------------------------------------
// K_A: agg[n][o] = conv_bias[o] + sum_i x[n][i] * root_w[i][o]
// ---------------------------------------------------------------------------
__global__ __launch_bounds__(256) void k_init2(const float* __restrict__ x,
                                               const float* __restrict__ root_w,
                                               const float* __restrict__ conv_bias,
                                               float* __restrict__ agg) {
    __shared__ float rw[NODE_DIM * HIDDEN_DIM];   // 8KB
    __shared__ float cb[HIDDEN_DIM];
    __shared__ float xS[128 * NODE_DIM];          // 16KB
    for (int t = threadIdx.x; t < NODE_DIM * HIDDEN_DIM; t += 256) rw[t] = root_w[t];
    if (threadIdx.x < HIDDEN_DIM) cb[threadIdx.x] = conv_bias[threadIdx.x];
    const int nb = blockIdx.x * 128;
    {
        const float4* xg = (const float4*)x;
        float4* xs4 = (float4*)xS;
        #pragma unroll
        for (int r = 0; r < 4; ++r) {
            int t = r * 256 + threadIdx.x;
            int gi = nb * (NODE_DIM / 4) + t;
            xs4[t] = (gi < NUM_NODES * (NODE_DIM / 4)) ? xg[gi] : make_float4(0.f, 0.f, 0.f, 0.f);
        }
    }
    __syncthreads();
    const int lane = threadIdx.x & 63;
    const int w    = threadIdx.x >> 6;
    for (int r = 0; r < 32; ++r) {
        const int n = nb + w * 32 + r;
        if (n >= NUM_NODES) break;                 // wave-uniform
        float acc = cb[lane];
        const float* xr = &xS[(w * 32 + r) * NODE_DIM];
        #pragma unroll
        for (int i = 0; i < NODE_DIM; ++i)
            acc = fmaf(xr[i], rw[i * HIDDEN_DIM + lane], acc);
        agg[n * HIDDEN_DIM + lane] = acc;
    }
}

// ---------------------------------------------------------------------------
// K_B: fused NNConv message + scatter (unchanged from round 3).
// ---------------------------------------------------------------------------
#define MB 4
__global__ __launch_bounds__(512) void k_msg(const int* __restrict__ ei,
                                             const float* __restrict__ ea,
                                             const float* __restrict__ x,
                                             const float* __restrict__ w_nn,
                                             const float* __restrict__ b_nn,
                                             float* __restrict__ agg) {
    __shared__ float4 wAs[NODE_DIM * HIDDEN_DIM]; // [32][64] float4 = 32KB
    __shared__ float4 wBs[NODE_DIM * HIDDEN_DIM]; // 32KB
    __shared__ float  xS[8][MB * NODE_DIM];       // 4KB
    __shared__ float  eS[8][MB][8];               // 1KB
    for (int t = threadIdx.x; t < NODE_DIM * HIDDEN_DIM; t += 512) {
        wAs[t] = make_float4(w_nn[t],            w_nn[2048 + t],
                             w_nn[2 * 2048 + t], w_nn[3 * 2048 + t]);
        wBs[t] = make_float4(w_nn[4 * 2048 + t], w_nn[5 * 2048 + t],
                             w_nn[6 * 2048 + t], b_nn[t]);
    }
    __syncthreads();

    const int lane   = threadIdx.x & 63;
    const int ws     = threadIdx.x >> 6;
    const int wave   = (blockIdx.x * blockDim.x + threadIdx.x) >> 6;
    const int nwaves = (gridDim.x * blockDim.x) >> 6;
    const int* __restrict__ srcs = ei;
    const int* __restrict__ dsts = ei + NUM_EDGES;
    const int em = lane / EDGE_DIM, ek = lane % EDGE_DIM;

    for (int e0 = wave * MB; e0 < NUM_EDGES; e0 += nwaves * MB) {
        {
            const int ii = lane & 31;
            #pragma unroll
            for (int rep = 0; rep < 2; ++rep) {
                const int m = rep * 2 + (lane >> 5);
                xS[ws][m * NODE_DIM + ii] = x[srcs[e0 + m] * NODE_DIM + ii];
            }
            if (lane < MB * EDGE_DIM) eS[ws][em][ek] = ea[e0 * EDGE_DIM + lane];
        }
        int    dst[MB];
        float4 ev0[MB], ev1[MB];
        float  acc[MB];
        #pragma unroll
        for (int m = 0; m < MB; ++m) {
            dst[m] = dsts[e0 + m];
            const float4* ep = (const float4*)&eS[ws][m][0];
            ev0[m] = ep[0]; ev1[m] = ep[1];
            acc[m] = 0.f;
        }

        #pragma unroll 8
        for (int i = 0; i < NODE_DIM; ++i) {
            const float4 a = wAs[i * HIDDEN_DIM + lane];
            const float4 b = wBs[i * HIDDEN_DIM + lane];
            #pragma unroll
            for (int m = 0; m < MB; ++m) {
                float t = b.w;
                t = fmaf(ev0[m].x, a.x, t); t = fmaf(ev0[m].y, a.y, t);
                t = fmaf(ev0[m].z, a.z, t); t = fmaf(ev0[m].w, a.w, t);
                t = fmaf(ev1[m].x, b.x, t); t = fmaf(ev1[m].y, b.y, t);
                t = fmaf(ev1[m].z, b.z, t);
                t = fmaxf(t, 0.f);
                acc[m] = fmaf(xS[ws][m * NODE_DIM + i], t, acc[m]);
            }
        }

        #pragma unroll
        for (int m = 0; m < MB; ++m)
            atomicAdd(&agg[dst[m] * HIDDEN_DIM + lane], acc[m]);
    }
}

// ---------------------------------------------------------------------------
// K_C v3: classifier as bf16 MFMA GEMM.
// Block = 256 thr = 4 waves = 64 edges. A-tile [64][ASTRIDE] bf16 in LDS:
// row e = [relu(h_src) x64, relu(h_dst) x64, ea x7, 1.0, 0 x24].
// Wave w computes edges w*16..w*16+15 x all 64 outputs: 5 K-steps x 4 N-tiles.
// Epilogue: z=relu(acc); out = z @ w_e2 + b_e2 via 16-lane shfl reduction.
// ---------------------------------------------------------------------------
#define ASTRIDE 168   // bf16 elems per A row = 336B: 16B-aligned, 2-way banks (free)
__global__ __launch_bounds__(256) void k_edge3(const int* __restrict__ ei,
                                               const float* __restrict__ ea,
                                               const float* __restrict__ agg,
                                               const ushort* __restrict__ bfrag,
                                               const float* __restrict__ w_e2,
                                               const float* __restrict__ b_e2,
                                               float* __restrict__ out) {
    __shared__ ushort aS[64 * ASTRIDE];   // 21504B
    __shared__ ushort bS[5 * 4 * 64 * 8]; // 20480B
    __shared__ float  w2S[128];
    {
        const uint4* g = (const uint4*)bfrag;    // 20480B = 1280 uint4
        uint4* s = (uint4*)bS;
        for (int t = threadIdx.x; t < 1280; t += 256) s[t] = g[t];
        if (threadIdx.x < 128) w2S[threadIdx.x] = w_e2[threadIdx.x];
    }
    const int e0 = blockIdx.x * 64;
    // ---- stage A tile: 4 threads per edge ----
    {
        const int el = threadIdx.x >> 2;          // 0..63
        const int q  = threadIdx.x & 3;           // quarter of the 64-float h rows
        const int e  = e0 + el;
        const int src = ei[e], dst = ei[NUM_EDGES + e];
        const float4* ps = (const float4*)(agg + (size_t)src * HIDDEN_DIM + q * 16);
        const float4* pd = (const float4*)(agg + (size_t)dst * HIDDEN_DIM + q * 16);
        unsigned* arow = (unsigned*)(aS + el * ASTRIDE);
        #pragma unroll
        for (int i = 0; i < 4; ++i) {
            float4 s = ps[i];
            arow[q * 8 + i * 2 + 0] = pack2bf(fmaxf(s.x, 0.f), fmaxf(s.y, 0.f));
            arow[q * 8 + i * 2 + 1] = pack2bf(fmaxf(s.z, 0.f), fmaxf(s.w, 0.f));
        }
        #pragma unroll
        for (int i = 0; i < 4; ++i) {
            float4 d = pd[i];
            arow[32 + q * 8 + i * 2 + 0] = pack2bf(fmaxf(d.x, 0.f), fmaxf(d.y, 0.f));
            arow[32 + q * 8 + i * 2 + 1] = pack2bf(fmaxf(d.z, 0.f), fmaxf(d.w, 0.f));
        }
        if (q == 0) {   // ea(7) + 1.0 at k=128..135 (uints 64..67)
            float ev[8];
            #pragma unroll
            for (int k = 0; k < EDGE_DIM; ++k) ev[k] = ea[e * EDGE_DIM + k];
            ev[7] = 1.0f;
            #pragma unroll
            for (int i = 0; i < 4; ++i)
                arow[64 + i] = pack2bf(ev[2 * i], ev[2 * i + 1]);
        } else {        // zero pad k=136..159 (uints 68..79)
            unsigned* z = arow + 64 + q * 4;
            z[0] = 0u; z[1] = 0u; z[2] = 0u; z[3] = 0u;
        }
    }
    __syncthreads();

    const int lane = threadIdx.x & 63;
    const int w    = threadIdx.x >> 6;
    f32x4 acc[4];
    #pragma unroll
    for (int nt = 0; nt < 4; ++nt) acc[nt] = (f32x4){0.f, 0.f, 0.f, 0.f};

    const ushort* arow = aS + (w * 16 + (lane & 15)) * ASTRIDE + (lane >> 4) * 8;
    #pragma unroll
    for (int ks = 0; ks < 5; ++ks) {
        bf16x8 af = *(const bf16x8*)(arow + ks * 32);
        #pragma unroll
        for (int nt = 0; nt < 4; ++nt) {
            bf16x8 bf = *(const bf16x8*)(bS + ((ks * 4 + nt) * 64 + lane) * 8);
            acc[nt] = __builtin_amdgcn_mfma_f32_16x16x32_bf16(af, bf, acc[nt], 0, 0, 0);
        }
    }

    // ---- epilogue: z = relu(acc); out = z @ w_e2 + b_e2 ----
    float w20[4], w21[4];
    #pragma unroll
    for (int nt = 0; nt < 4; ++nt) {
        int o = nt * 16 + (lane & 15);
        w20[nt] = w2S[o * 2 + 0];
        w21[nt] = w2S[o * 2 + 1];
    }
    const float bias0 = b_e2[0], bias1 = b_e2[1];
    #pragma unroll
    for (int r = 0; r < 4; ++r) {
        float p0 = 0.f, p1 = 0.f;
        #pragma unroll
        for (int nt = 0; nt < 4; ++nt) {
            float z = fmaxf(acc[nt][r], 0.f);
            p0 = fmaf(z, w20[nt], p0);
            p1 = fmaf(z, w21[nt], p1);
        }
        #pragma unroll
        for (int off = 1; off < 16; off <<= 1) {
            p0 += __shfl_xor(p0, off);
            p1 += __shfl_xor(p1, off);
        }
        if ((lane & 15) == 0) {
            int e = e0 + w * 16 + (lane >> 4) * 4 + r;
            float2 v; v.x = p0 + bias0; v.y = p1 + bias1;
            ((float2*)out)[e] = v;
        }
    }
}

// ---------------------------------------------------------------------------
extern "C" void kernel_launch(void* const* d_in, const int* in_sizes, int n_in,
                              void* d_out, int out_size, void* d_ws, size_t ws_size,
                              hipStream_t stream) {
    const int*   ei        = (const int*)d_in[0];
    const float* edge_attr = (const float*)d_in[1];
    const float* node_emb  = (const float*)d_in[2];
    const float* w_nn      = (const float*)d_in[3];
    const float* b_nn      = (const float*)d_in[4];
    const float* root_w    = (const float*)d_in[5];
    const float* conv_bias = (const float*)d_in[6];
    const float* w_e1      = (const float*)d_in[7];
    const float* b_e1      = (const float*)d_in[8];
    const float* w_e2      = (const float*)d_in[9];
    const float* b_e2      = (const float*)d_in[10];
    float*       out       = (float*)d_out;
    float*       agg       = (float*)d_ws;  // [N,64] f32 = 12.8 MB
    ushort*      bfrag     = (ushort*)((char*)d_ws + (size_t)NUM_NODES * HIDDEN_DIM * 4); // 20.5KB

    // K_P: pre-packed B fragments (w_e1 + folded b_e1, bf16)
    k_prep<<<(5 * 4 * 64 * 8 + 255) / 256, 256, 0, stream>>>(w_e1, b_e1, bfrag);
    // K_A: agg = x @ root_w + conv_bias
    k_init2<<<(NUM_NODES + 127) / 128, 256, 0, stream>>>(node_emb, root_w, conv_bias, agg);
    // K_B: fused edge-MLP + per-edge matmul + scatter-add
    k_msg<<<512, 512, 0, stream>>>(ei, edge_attr, node_emb, w_nn, b_nn, agg);
    // K_C: classifier GEMM (3125 blocks x 64 edges)
    k_edge3<<<NUM_EDGES / 64, 256, 0, stream>>>(ei, edge_attr, agg, bfrag, w_e2, b_e2, out);
}